// Round 8
// baseline (1369.813 us; speedup 1.0000x reference)
//
#include <hip/hip_runtime.h>
#include <hip/hip_cooperative_groups.h>
namespace cg = cooperative_groups;

#define NN 50000
#define NE 800000
#define INC 32
#define HH 64
#define H2 128
#define OC 16
#define ON 17
#define NL 4
#define MEPS 1e-7f
#define LNE 1e-5f
#define NTHR 256
#define T32 1563             /* ceil(50000/32) */
#define SCAN_BLOCKS 196      /* ceil(50000/256) */

// ---------- ordered-uint encoding for float atomic max ----------
__device__ __forceinline__ unsigned fenc(float x) {
    unsigned u = __float_as_uint(x);
    return (u & 0x80000000u) ? ~u : (u | 0x80000000u);
}
__device__ __forceinline__ float fdec(unsigned u) {
    return (u & 0x80000000u) ? __uint_as_float(u & 0x7fffffffu)
                             : __uint_as_float(~u);
}
// ---------- bf16 helpers (RNE) ----------
__device__ __forceinline__ unsigned short f2b(float x) {
    unsigned b = __float_as_uint(x);
    b += 0x7FFFu + ((b >> 16) & 1u);
    return (unsigned short)(b >> 16);
}
__device__ __forceinline__ float b2f(unsigned short u) {
    return __uint_as_float(((unsigned)u) << 16);
}

struct MegaArgs {
    const float *x, *nodeW, *nodeB, *W1, *b1, *mlg, *mlb, *W2, *b2, *tt, *lng, *lnb;
    const int *esrc, *edst;
    const float *gW, *gb, *nW, *nbp;
    float* out;
    int* counts; int* rank; int2* rowse; int* ssrc; int* gcur; unsigned* genc;
    float* h; unsigned short* hbf;
    float* y0; unsigned short* yb0; float* y1; unsigned short* yb1;
};

// Static LDS: 8192 floats = 32 KB -> >=2 blocks/CU under any occupancy calculator.
__global__ __launch_bounds__(NTHR, 2) void k_mega(MegaArgs a) {
    __shared__ float smf[8192];
    int* smi = (int*)smf;
    cg::grid_group grid = cg::this_grid();
    const int tid = threadIdx.x;
    const int bid = blockIdx.x;
    const int G = gridDim.x;
    const int gid = bid * NTHR + tid;
    const int lane = tid & 63;
    const int wid = tid >> 6;
    const int tx = tid & 15, ty = tid >> 4;

    // ---- phase 0: zero counts/gcur/genc (ws is 0xAA-poisoned each replay) ----
    for (int i = gid; i < NN + 1 + OC; i += G * NTHR) {
        if (i < NN) a.counts[i] = 0;
        else if (i == NN) *a.gcur = 0;
        else a.genc[i - NN - 1] = 0u;
    }
    grid.sync();

    // ---- phase 1: hist + rank ----
    for (int e = gid; e < NE; e += G * NTHR)
        a.rank[e] = atomicAdd(&a.counts[a.edst[e]], 1);
    grid.sync();

    // ---- phase 2: scan (block-local inclusive + atomic base reservation) ----
    if (bid < SCAN_BLOCKS) {
        int i = bid * NTHR + tid;
        int v = (i < NN) ? a.counts[i] : 0;
        smi[tid] = v;
        __syncthreads();
        for (int off = 1; off < NTHR; off <<= 1) {
            int xv = (tid >= off) ? smi[tid - off] : 0;
            __syncthreads();
            smi[tid] += xv;
            __syncthreads();
        }
        if (tid == 0) smi[NTHR] = atomicAdd(a.gcur, smi[NTHR - 1]);
        __syncthreads();
        if (i < NN) a.rowse[i] = make_int2(smi[NTHR] + smi[tid] - v, v);
    }
    grid.sync();

    // ---- phase 3: scatter (no atomics) ----
    for (int e = gid; e < NE; e += G * NTHR)
        a.ssrc[a.rowse[a.edst[e]].x + a.rank[e]] = a.esrc[e];
    grid.sync();

    // ---- phase 4: encoder h = x @ W + b, + bf16 shadow ----
    {
        float* Ws = smf; float* bs = smf + 2048;
        for (int i = tid; i < INC * HH; i += NTHR) Ws[i] = a.nodeW[i];
        if (tid < HH) bs[tid] = a.nodeB[tid];
        __syncthreads();
        for (int n = bid * 4 + wid; n < NN; n += G * 4) {
            float v = (lane < INC) ? a.x[(size_t)n * INC + lane] : 0.f;
            float acc = bs[lane];
            #pragma unroll
            for (int k = 0; k < INC; ++k)
                acc += __shfl(v, k) * Ws[k * HH + lane];
            a.h[(size_t)n * HH + lane] = acc;
            a.hbf[(size_t)n * HH + lane] = f2b(acc);
        }
    }
    grid.sync();

    // ---- layers: fully fused agg -> gemmA -> LN -> gemmB per 32-node tile ----
    const int slot = lane >> 3, oc8 = lane & 7;
    for (int l = 0; l < NL; ++l) {
        const float* yin; const unsigned short* ybin;
        if (l == 0) { yin = a.h; ybin = a.hbf; }
        else if (((l - 1) & 1) == 0) { yin = a.y0; ybin = a.yb0; }
        else { yin = a.y1; ybin = a.yb1; }
        float* ynext = (l & 1) ? a.y1 : a.y0;
        unsigned short* ybnext = (l & 1) ? a.yb1 : a.yb0;
        const bool has_next = (l < NL - 1);
        const bool has_res = (l > 0);
        const float tval = a.tt[l];
        const float* W1l = a.W1 + (size_t)l * HH * H2;
        const float* b1l = a.b1 + (size_t)l * H2;
        const float* lgl = a.mlg + (size_t)l * H2;
        const float* lbl = a.mlb + (size_t)l * H2;
        const float* W2l = a.W2 + (size_t)l * H2 * HH;
        const float* b2l = a.b2 + (size_t)l * HH;
        const float* nlgl = a.lng + (size_t)(l + 1) * HH;
        const float* nlbl = a.lnb + (size_t)(l + 1) * HH;

        float* UA  = smf;          // As (32x68) then Us (32x132), overlaid
        float* bb1 = smf + 4224;   // 128
        float* bb2 = smf + 4352;   // 64
        float* lgv = smf + 4416;   // 128
        float* lbv = smf + 4544;   // 128
        float* ps  = smf + 4672;   // 256
        float* psq = smf + 4928;   // 256
        float* mus = smf + 5184;   // 32
        float* rss = smf + 5216;   // 32
        if (tid < H2) { bb1[tid] = b1l[tid]; lgv[tid] = lgl[tid]; lbv[tid] = lbl[tid]; }
        if (tid < HH) bb2[tid] = b2l[tid];

        for (int t = bid; t < T32; t += G) {
            // ---- agg: wave handles 8 nodes, wide uint4 gathers ----
            for (int i = 0; i < 8; ++i) {
                int node = t * 32 + wid * 8 + i;
                float val = 0.f;
                if (node < NN) {
                    int2 se = a.rowse[node];
                    int start = se.x, deg = se.y;
                    float Sa[8] = {0.f,0.f,0.f,0.f,0.f,0.f,0.f,0.f};
                    float Sm[8] = {0.f,0.f,0.f,0.f,0.f,0.f,0.f,0.f};
                    if (deg > 0 && deg <= 64) {
                        int myidx = (lane < deg) ? a.ssrc[start + lane] : 0;
                        for (int base = 0; base < deg; base += 8) {
                            int e = base + slot;
                            int ec = (e < deg) ? e : (deg - 1);
                            int s = __shfl(myidx, ec);
                            uint4 vv = *((const uint4*)(ybin + (size_t)s * HH) + oc8);
                            bool ok = e < deg;
                            unsigned wv[4] = {vv.x, vv.y, vv.z, vv.w};
                            #pragma unroll
                            for (int j = 0; j < 4; ++j) {
                                float mlo = fmaxf(b2f((unsigned short)(wv[j] & 0xffffu)), 0.f) + MEPS;
                                float mhi = fmaxf(b2f((unsigned short)(wv[j] >> 16)), 0.f) + MEPS;
                                float alo = ok ? __expf(tval * mlo) : 0.f;
                                float ahi = ok ? __expf(tval * mhi) : 0.f;
                                Sa[2*j]   += alo; Sm[2*j]   += mlo * alo;
                                Sa[2*j+1] += ahi; Sm[2*j+1] += mhi * ahi;
                            }
                        }
                    } else if (deg > 64) {
                        for (int ob = 0; ob < deg; ob += 64) {
                            int dd = deg - ob; if (dd > 64) dd = 64;
                            int myidx = (lane < dd) ? a.ssrc[start + ob + lane] : 0;
                            for (int base = 0; base < dd; base += 8) {
                                int e = base + slot;
                                int ec = (e < dd) ? e : (dd - 1);
                                int s = __shfl(myidx, ec);
                                uint4 vv = *((const uint4*)(ybin + (size_t)s * HH) + oc8);
                                bool ok = e < dd;
                                unsigned wv[4] = {vv.x, vv.y, vv.z, vv.w};
                                #pragma unroll
                                for (int j = 0; j < 4; ++j) {
                                    float mlo = fmaxf(b2f((unsigned short)(wv[j] & 0xffffu)), 0.f) + MEPS;
                                    float mhi = fmaxf(b2f((unsigned short)(wv[j] >> 16)), 0.f) + MEPS;
                                    float alo = ok ? __expf(tval * mlo) : 0.f;
                                    float ahi = ok ? __expf(tval * mhi) : 0.f;
                                    Sa[2*j]   += alo; Sm[2*j]   += mlo * alo;
                                    Sa[2*j+1] += ahi; Sm[2*j+1] += mhi * ahi;
                                }
                            }
                        }
                    }
                    #pragma unroll
                    for (int msk = 8; msk < 64; msk <<= 1) {
                        #pragma unroll
                        for (int j = 0; j < 8; ++j) {
                            Sa[j] += __shfl_xor(Sa[j], msk);
                            Sm[j] += __shfl_xor(Sm[j], msk);
                        }
                    }
                    float Saf = 0.f, Smf = 0.f;
                    int srcl = lane >> 3, want = lane & 7;
                    #pragma unroll
                    for (int j = 0; j < 8; ++j) {
                        float t1 = __shfl(Sa[j], srcl);
                        float t2 = __shfl(Sm[j], srcl);
                        if (want == j) { Saf = t1; Smf = t2; }
                    }
                    val = Smf / fmaxf(Saf, MEPS) + yin[(size_t)node * HH + lane];
                }
                UA[(wid * 8 + i) * 68 + lane] = val;
            }
            __syncthreads();
            // ---- gemmA: As(LDS) x W1(global, L1-resident) -> regs ----
            int r0 = ty * 2, j0 = tx * 8;
            float accA[2][8] = {};
            #pragma unroll 4
            for (int k = 0; k < HH; ++k) {
                float4 b0  = *(const float4*)(W1l + (size_t)k * H2 + j0);
                float4 b1v = *(const float4*)(W1l + (size_t)k * H2 + j0 + 4);
                #pragma unroll
                for (int r = 0; r < 2; ++r) {
                    float av = UA[(r0 + r) * 68 + k];
                    accA[r][0] += av * b0.x;  accA[r][1] += av * b0.y;
                    accA[r][2] += av * b0.z;  accA[r][3] += av * b0.w;
                    accA[r][4] += av * b1v.x; accA[r][5] += av * b1v.y;
                    accA[r][6] += av * b1v.z; accA[r][7] += av * b1v.w;
                }
            }
            __syncthreads();   // all reads of As done -> overlay Us
            #pragma unroll
            for (int r = 0; r < 2; ++r) {
                float* up = UA + (r0 + r) * 132 + j0;
                #pragma unroll
                for (int j = 0; j < 8; ++j) up[j] = accA[r][j] + bb1[j0 + j];
            }
            __syncthreads();
            // ---- LN(128)+ReLU on Us ----
            {
                int row = tid >> 3, q = tid & 7;
                const float* rp = UA + row * 132;
                float s = 0.f, sq = 0.f;
                #pragma unroll
                for (int i = 0; i < 16; ++i) { float v = rp[q + 8 * i]; s += v; sq += v * v; }
                ps[row * 8 + q] = s; psq[row * 8 + q] = sq;
            }
            __syncthreads();
            if (tid < 32) {
                float s = 0.f, sq = 0.f;
                #pragma unroll
                for (int j = 0; j < 8; ++j) { s += ps[tid * 8 + j]; sq += psq[tid * 8 + j]; }
                float mu = s * (1.f / 128.f);
                float var = sq * (1.f / 128.f) - mu * mu;
                mus[tid] = mu;
                rss[tid] = rsqrtf(fmaxf(var, 0.f) + LNE);
            }
            __syncthreads();
            {
                int row = tid >> 3, q = tid & 7;
                float mu = mus[row], rs = rss[row];
                float* rp = UA + row * 132;
                #pragma unroll
                for (int i = 0; i < 16; ++i) {
                    int c = q + 8 * i;
                    rp[c] = fmaxf((rp[c] - mu) * rs * lgv[c] + lbv[c], 0.f);
                }
            }
            __syncthreads();
            // ---- gemmB: Us(LDS) x W2(global) ----
            int o0 = tx * 4;
            float acc2[2][4] = {};
            #pragma unroll 4
            for (int k = 0; k < H2; ++k) {
                float4 b4 = *(const float4*)(W2l + (size_t)k * HH + o0);
                #pragma unroll
                for (int r = 0; r < 2; ++r) {
                    float av = UA[(r0 + r) * 132 + k];
                    acc2[r][0] += av * b4.x; acc2[r][1] += av * b4.y;
                    acc2[r][2] += av * b4.z; acc2[r][3] += av * b4.w;
                }
            }
            float o[2][4];
            #pragma unroll
            for (int r = 0; r < 2; ++r) {
                int n = t * 32 + r0 + r;
                o[r][0] = acc2[r][0] + bb2[o0];     o[r][1] = acc2[r][1] + bb2[o0 + 1];
                o[r][2] = acc2[r][2] + bb2[o0 + 2]; o[r][3] = acc2[r][3] + bb2[o0 + 3];
                if (n < NN) {
                    if (has_res) {
                        float4 hr = *(const float4*)(a.h + (size_t)n * HH + o0);
                        o[r][0] += hr.x; o[r][1] += hr.y; o[r][2] += hr.z; o[r][3] += hr.w;
                    }
                    float4 ov = {o[r][0], o[r][1], o[r][2], o[r][3]};
                    *(float4*)(a.h + (size_t)n * HH + o0) = ov;
                }
            }
            if (has_next) {
                float g0 = nlgl[o0], g1 = nlgl[o0 + 1], g2 = nlgl[o0 + 2], g3 = nlgl[o0 + 3];
                float c0 = nlbl[o0], c1 = nlbl[o0 + 1], c2 = nlbl[o0 + 2], c3 = nlbl[o0 + 3];
                #pragma unroll
                for (int r = 0; r < 2; ++r) {
                    int n = t * 32 + r0 + r;
                    float s = o[r][0] + o[r][1] + o[r][2] + o[r][3];
                    float sq = o[r][0]*o[r][0] + o[r][1]*o[r][1] + o[r][2]*o[r][2] + o[r][3]*o[r][3];
                    #pragma unroll
                    for (int m = 1; m < 16; m <<= 1) { s += __shfl_xor(s, m); sq += __shfl_xor(sq, m); }
                    float mu = s * (1.f / 64.f);
                    float var = sq * (1.f / 64.f) - mu * mu;
                    float rs = rsqrtf(fmaxf(var, 0.f) + LNE);
                    if (n < NN) {
                        float y0v = fmaxf((o[r][0] - mu) * rs * g0 + c0, 0.f);
                        float y1v = fmaxf((o[r][1] - mu) * rs * g1 + c1, 0.f);
                        float y2v = fmaxf((o[r][2] - mu) * rs * g2 + c2, 0.f);
                        float y3v = fmaxf((o[r][3] - mu) * rs * g3 + c3, 0.f);
                        float4 yv = {y0v, y1v, y2v, y3v};
                        *(float4*)(ynext + (size_t)n * HH + o0) = yv;
                        ushort4 bv;
                        bv.x = f2b(y0v); bv.y = f2b(y1v); bv.z = f2b(y2v); bv.w = f2b(y3v);
                        *(ushort4*)(ybnext + (size_t)n * HH + o0) = bv;
                    }
                }
            }
            __syncthreads();   // protect UA before next tile
        }
        if (l < NL - 1) grid.sync();   // next layer gathers ynext cross-block
    }
    // h for head is same-block 32-tile mapping -> no grid sync needed here

    // ---- final LN + both heads (32-row tiles) ----
    {
        float* As  = smf;            // 2176
        float* Wc  = smf + 2176;     // 2560
        float* Os  = smf + 4736;     // 1280
        float* bsv = smf + 6016;     // 40
        float* lgv = smf + 6056;     // 64
        float* lbv = smf + 6120;     // 64
        float* ps  = smf + 6184;     // 256
        float* psq = smf + 6440;     // 256
        float* mus = smf + 6696;     // 32
        float* rss = smf + 6728;     // 32
        for (int i = tid; i < HH * ON; i += NTHR) { int k = i / ON, j = i - k * ON; Wc[k * 40 + j] = a.nW[i]; }
        for (int i = tid; i < HH * OC; i += NTHR) { int k = i / OC, j = i - k * OC; Wc[k * 40 + ON + j] = a.gW[i]; }
        if (tid < ON) bsv[tid] = a.nbp[tid];
        else if (tid < 33) bsv[tid] = a.gb[tid - ON];
        if (tid < HH) { lgv[tid] = a.lng[tid]; lbv[tid] = a.lnb[tid]; }
        for (int t = bid; t < T32; t += G) {
            {
                int row = tid >> 3, cb = (tid & 7) * 8;
                int n = t * 32 + row;
                float4* dp = (float4*)(As + row * 68 + cb);
                if (n < NN) {
                    const float4* sp = (const float4*)(a.h + (size_t)n * HH + cb);
                    dp[0] = sp[0]; dp[1] = sp[1];
                } else {
                    float4 z = {0.f, 0.f, 0.f, 0.f};
                    dp[0] = z; dp[1] = z;
                }
            }
            __syncthreads();
            {
                int row = tid >> 3, q = tid & 7;
                const float* rp = As + row * 68;
                float s = 0.f, sq = 0.f;
                #pragma unroll
                for (int i = 0; i < 8; ++i) { float v = rp[q + 8 * i]; s += v; sq += v * v; }
                ps[row * 8 + q] = s; psq[row * 8 + q] = sq;
            }
            __syncthreads();
            if (tid < 32) {
                float s = 0.f, sq = 0.f;
                #pragma unroll
                for (int j = 0; j < 8; ++j) { s += ps[tid * 8 + j]; sq += psq[tid * 8 + j]; }
                float mu = s * (1.f / 64.f);
                float var = sq * (1.f / 64.f) - mu * mu;
                mus[tid] = mu;
                rss[tid] = rsqrtf(fmaxf(var, 0.f) + LNE);
            }
            __syncthreads();
            {
                int row = tid >> 3, q = tid & 7;
                float mu = mus[row], rs = rss[row];
                float* rp = As + row * 68;
                #pragma unroll
                for (int i = 0; i < 8; ++i) {
                    int c = q + 8 * i;
                    rp[c] = fmaxf((rp[c] - mu) * rs * lgv[c] + lbv[c], 0.f);
                }
            }
            __syncthreads();
            int r0 = ty * 2;
            float acc[2][3];
            #pragma unroll
            for (int r = 0; r < 2; ++r) {
                acc[r][0] = bsv[tx]; acc[r][1] = bsv[tx + 16]; acc[r][2] = bsv[32];
            }
            #pragma unroll 4
            for (int k = 0; k < HH; ++k) {
                float w0 = Wc[k * 40 + tx];
                float w1 = Wc[k * 40 + 16 + tx];
                float w2 = Wc[k * 40 + 32];
                #pragma unroll
                for (int r = 0; r < 2; ++r) {
                    float av = As[(r0 + r) * 68 + k];
                    acc[r][0] += av * w0; acc[r][1] += av * w1; acc[r][2] += av * w2;
                }
            }
            #pragma unroll
            for (int r = 0; r < 2; ++r) {
                Os[(r0 + r) * 40 + tx] = acc[r][0];
                Os[(r0 + r) * 40 + 16 + tx] = acc[r][1];
                if (tx == 0) Os[(r0 + r) * 40 + 32] = acc[r][2];
            }
            __syncthreads();
            for (int i = tid; i < 32 * ON; i += NTHR) {
                int r = i / ON, j = i - r * ON;
                int n = t * 32 + r;
                if (n < NN) a.out[OC + (size_t)n * ON + j] = Os[r * 40 + j];
            }
            if (tid < OC) {
                int rmax = NN - t * 32; if (rmax > 32) rmax = 32;
                float m = -INFINITY;
                for (int r = 0; r < rmax; ++r) m = fmaxf(m, Os[r * 40 + ON + tid]);
                atomicMax(&a.genc[tid], fenc(m));
            }
            __syncthreads();
        }
    }
    grid.sync();
    if (bid == 0 && tid < OC) a.out[tid] = fdec(a.genc[tid]);
}

// ---------- launch ----------
extern "C" void kernel_launch(void* const* d_in, const int* in_sizes, int n_in,
                              void* d_out, int out_size, void* d_ws, size_t ws_size,
                              hipStream_t stream) {
    char* ws = (char*)d_ws;
    size_t off = 0;
    auto alloc = [&](size_t bytes) -> void* {
        void* p = ws + off;
        off = (off + bytes + 255) & ~(size_t)255;
        return p;
    };
    MegaArgs a;
    a.x     = (const float*)d_in[0];
    a.nodeW = (const float*)d_in[1];
    a.nodeB = (const float*)d_in[2];
    a.W1    = (const float*)d_in[3];
    a.b1    = (const float*)d_in[4];
    a.mlg   = (const float*)d_in[5];
    a.mlb   = (const float*)d_in[6];
    a.W2    = (const float*)d_in[7];
    a.b2    = (const float*)d_in[8];
    a.tt    = (const float*)d_in[9];
    a.lng   = (const float*)d_in[10];
    a.lnb   = (const float*)d_in[11];
    const int* ei = (const int*)d_in[12];
    a.esrc  = ei;
    a.edst  = ei + NE;
    a.gW    = (const float*)d_in[13];
    a.gb    = (const float*)d_in[14];
    a.nW    = (const float*)d_in[15];
    a.nbp   = (const float*)d_in[16];
    a.out   = (float*)d_out;

    a.counts = (int*)alloc((size_t)NN * 4);
    a.gcur   = (int*)alloc(64);
    a.genc   = (unsigned*)alloc(64);
    a.rowse  = (int2*)alloc((size_t)NN * 8);
    a.rank   = (int*)alloc((size_t)NE * 4);
    a.ssrc   = (int*)alloc((size_t)NE * 4);
    a.h      = (float*)alloc((size_t)NN * HH * 4);
    a.hbf    = (unsigned short*)alloc((size_t)NN * HH * 2);
    a.y0     = (float*)alloc((size_t)NN * HH * 4);
    a.yb0    = (unsigned short*)alloc((size_t)NN * HH * 2);
    a.y1     = (float*)alloc((size_t)NN * HH * 4);
    a.yb1    = (unsigned short*)alloc((size_t)NN * HH * 2);

    // Runtime-sized cooperative grid: never exceed guaranteed co-residency.
    int occ = 0;
    hipError_t qe = hipOccupancyMaxActiveBlocksPerMultiprocessor(&occ, k_mega, NTHR, 0);
    int grid = (qe == hipSuccess && occ >= 1) ? occ * 256 : 256;
    if (grid > 512) grid = 512;
    if (grid < 256) grid = 256;   // >= SCAN_BLOCKS(196)

    void* params[] = {(void*)&a};
    hipLaunchCooperativeKernel((const void*)k_mega, dim3(grid), dim3(NTHR),
                               params, 0, stream);
}

// Round 9
// 573.563 us; speedup vs baseline: 2.3883x; 2.3883x over previous
//
#include <hip/hip_runtime.h>

#define NN 50000
#define NE 800000
#define INC 32
#define HH 64
#define H2 128
#define OC 16
#define ON 17
#define NL 4
#define MEPS 1e-7f
#define LNE 1e-5f
#define NTHR 256
#define T32 1563             /* ceil(50000/32) */
#define SCAN_BLOCKS 196      /* ceil(50000/256) */

// ---------- ordered-uint encoding for float atomic max ----------
__device__ __forceinline__ unsigned fenc(float x) {
    unsigned u = __float_as_uint(x);
    return (u & 0x80000000u) ? ~u : (u | 0x80000000u);
}
__device__ __forceinline__ float fdec(unsigned u) {
    return (u & 0x80000000u) ? __uint_as_float(u & 0x7fffffffu)
                             : __uint_as_float(~u);
}
// ---------- bf16 helpers (RNE) ----------
__device__ __forceinline__ unsigned short f2b(float x) {
    unsigned b = __float_as_uint(x);
    b += 0x7FFFu + ((b >> 16) & 1u);
    return (unsigned short)(b >> 16);
}
__device__ __forceinline__ float b2f(unsigned short u) {
    return __uint_as_float(((unsigned)u) << 16);
}

// ---------- CSR build ----------
__global__ __launch_bounds__(256) void k_hist2(const int* __restrict__ dst, int* __restrict__ counts,
                                               int* __restrict__ rank) {
    int e = blockIdx.x * 256 + threadIdx.x;
    if (e < NE) rank[e] = atomicAdd(&counts[dst[e]], 1);
}

// single-pass scan: block reserves its output range via atomicAdd
__global__ __launch_bounds__(256) void k_scan(const int* __restrict__ counts,
                                              int2* __restrict__ rowse, int* __restrict__ gcur) {
    __shared__ int s[257];
    int t = threadIdx.x;
    int i = blockIdx.x * 256 + t;
    int v = (i < NN) ? counts[i] : 0;
    s[t] = v;
    __syncthreads();
    for (int off = 1; off < 256; off <<= 1) {
        int x = (t >= off) ? s[t - off] : 0;
        __syncthreads();
        s[t] += x;
        __syncthreads();
    }
    if (t == 0) s[256] = atomicAdd(gcur, s[255]);
    __syncthreads();
    if (i < NN) rowse[i] = make_int2(s[256] + s[t] - v, v);
}

__global__ __launch_bounds__(256) void k_scatter2(const int* __restrict__ src, const int* __restrict__ dst,
                                                  const int* __restrict__ rank, const int2* __restrict__ rowse,
                                                  int* __restrict__ ssrc) {
    int e = blockIdx.x * 256 + threadIdx.x;
    if (e < NE) ssrc[rowse[dst[e]].x + rank[e]] = src[e];
}

// ---------- node encoder: h = x @ W + b  + bf16 shadow ----------
__global__ __launch_bounds__(256) void k_encoder(const float* __restrict__ x, const float* __restrict__ W,
                                                 const float* __restrict__ b, float* __restrict__ h,
                                                 unsigned short* __restrict__ hbf) {
    __shared__ float Ws[INC * HH];
    __shared__ float bs[HH];
    int tid = threadIdx.x;
    for (int i = tid; i < INC * HH; i += 256) Ws[i] = W[i];
    if (tid < HH) bs[tid] = b[tid];
    __syncthreads();
    int wid = tid >> 6, lane = tid & 63;
    int n = blockIdx.x * 4 + wid;
    if (n >= NN) return;
    float v = (lane < INC) ? x[(size_t)n * INC + lane] : 0.f;
    float acc = bs[lane];
    #pragma unroll
    for (int k = 0; k < INC; ++k)
        acc += __shfl(v, k) * Ws[k * HH + lane];
    h[(size_t)n * HH + lane] = acc;
    hbf[(size_t)n * HH + lane] = f2b(acc);
}

// ---------- fused layer: agg -> gemmA -> LN(128)+ReLU -> gemmB -> +res
//            -> optional next-layer LN(64)+ReLU. One 32-node tile per block.
//            LDS ~21 KB, weights streamed from global (L2-resident). ----------
__global__ __launch_bounds__(256) void k_layer(const float* __restrict__ yin,
                                               const unsigned short* __restrict__ ybin,
                                               const int2* __restrict__ rowse,
                                               const int* __restrict__ ssrc,
                                               const float* __restrict__ tp,
                                               const float* __restrict__ W1l, const float* __restrict__ b1l,
                                               const float* __restrict__ lgl, const float* __restrict__ lbl,
                                               const float* __restrict__ W2l, const float* __restrict__ b2l,
                                               const float* __restrict__ hres, float* __restrict__ hout,
                                               const float* __restrict__ nlgl, const float* __restrict__ nlbl,
                                               float* __restrict__ ynext, unsigned short* __restrict__ ybnext) {
    __shared__ float UA[32 * 132];     // As (32x68) then Us (32x132), overlaid
    __shared__ float bb1[H2], bb2[HH];
    __shared__ float lgv[H2], lbv[H2];
    __shared__ float ps[256], psq[256];
    __shared__ float mus[32], rss[32];
    const int tid = threadIdx.x;
    const int t = blockIdx.x;
    const int lane = tid & 63;
    const int wid = tid >> 6;
    const int tx = tid & 15, ty = tid >> 4;
    const int slot = lane >> 3, oc8 = lane & 7;
    const float tval = *tp;
    if (tid < H2) { bb1[tid] = b1l[tid]; lgv[tid] = lgl[tid]; lbv[tid] = lbl[tid]; }
    if (tid < HH) bb2[tid] = b2l[tid];

    // ---- agg: each wave handles 8 nodes, wide uint4 gathers ----
    for (int i = 0; i < 8; ++i) {
        int node = t * 32 + wid * 8 + i;
        float val = 0.f;
        if (node < NN) {
            int2 se = rowse[node];
            int start = se.x, deg = se.y;
            float Sa[8] = {0.f,0.f,0.f,0.f,0.f,0.f,0.f,0.f};
            float Sm[8] = {0.f,0.f,0.f,0.f,0.f,0.f,0.f,0.f};
            if (deg > 0 && deg <= 64) {
                int myidx = (lane < deg) ? ssrc[start + lane] : 0;
                for (int base = 0; base < deg; base += 8) {
                    int e = base + slot;
                    int ec = (e < deg) ? e : (deg - 1);
                    int s = __shfl(myidx, ec);
                    uint4 vv = *((const uint4*)(ybin + (size_t)s * HH) + oc8);
                    bool ok = e < deg;
                    unsigned wv[4] = {vv.x, vv.y, vv.z, vv.w};
                    #pragma unroll
                    for (int j = 0; j < 4; ++j) {
                        float mlo = fmaxf(b2f((unsigned short)(wv[j] & 0xffffu)), 0.f) + MEPS;
                        float mhi = fmaxf(b2f((unsigned short)(wv[j] >> 16)), 0.f) + MEPS;
                        float alo = ok ? __expf(tval * mlo) : 0.f;
                        float ahi = ok ? __expf(tval * mhi) : 0.f;
                        Sa[2*j]   += alo; Sm[2*j]   += mlo * alo;
                        Sa[2*j+1] += ahi; Sm[2*j+1] += mhi * ahi;
                    }
                }
            } else if (deg > 64) {
                for (int ob = 0; ob < deg; ob += 64) {
                    int dd = deg - ob; if (dd > 64) dd = 64;
                    int myidx = (lane < dd) ? ssrc[start + ob + lane] : 0;
                    for (int base = 0; base < dd; base += 8) {
                        int e = base + slot;
                        int ec = (e < dd) ? e : (dd - 1);
                        int s = __shfl(myidx, ec);
                        uint4 vv = *((const uint4*)(ybin + (size_t)s * HH) + oc8);
                        bool ok = e < dd;
                        unsigned wv[4] = {vv.x, vv.y, vv.z, vv.w};
                        #pragma unroll
                        for (int j = 0; j < 4; ++j) {
                            float mlo = fmaxf(b2f((unsigned short)(wv[j] & 0xffffu)), 0.f) + MEPS;
                            float mhi = fmaxf(b2f((unsigned short)(wv[j] >> 16)), 0.f) + MEPS;
                            float alo = ok ? __expf(tval * mlo) : 0.f;
                            float ahi = ok ? __expf(tval * mhi) : 0.f;
                            Sa[2*j]   += alo; Sm[2*j]   += mlo * alo;
                            Sa[2*j+1] += ahi; Sm[2*j+1] += mhi * ahi;
                        }
                    }
                }
            }
            #pragma unroll
            for (int msk = 8; msk < 64; msk <<= 1) {
                #pragma unroll
                for (int j = 0; j < 8; ++j) {
                    Sa[j] += __shfl_xor(Sa[j], msk);
                    Sm[j] += __shfl_xor(Sm[j], msk);
                }
            }
            float Saf = 0.f, Smf = 0.f;
            int srcl = lane >> 3, want = lane & 7;
            #pragma unroll
            for (int j = 0; j < 8; ++j) {
                float t1 = __shfl(Sa[j], srcl);
                float t2 = __shfl(Sm[j], srcl);
                if (want == j) { Saf = t1; Smf = t2; }
            }
            val = Smf / fmaxf(Saf, MEPS) + yin[(size_t)node * HH + lane];
        }
        UA[(wid * 8 + i) * 68 + lane] = val;
    }
    __syncthreads();
    // ---- gemmA: As(LDS) x W1(global) -> regs ----
    int r0 = ty * 2, j0 = tx * 8;
    float accA[2][8] = {};
    #pragma unroll 4
    for (int k = 0; k < HH; ++k) {
        float4 b0  = *(const float4*)(W1l + (size_t)k * H2 + j0);
        float4 b1v = *(const float4*)(W1l + (size_t)k * H2 + j0 + 4);
        #pragma unroll
        for (int r = 0; r < 2; ++r) {
            float av = UA[(r0 + r) * 68 + k];
            accA[r][0] += av * b0.x;  accA[r][1] += av * b0.y;
            accA[r][2] += av * b0.z;  accA[r][3] += av * b0.w;
            accA[r][4] += av * b1v.x; accA[r][5] += av * b1v.y;
            accA[r][6] += av * b1v.z; accA[r][7] += av * b1v.w;
        }
    }
    __syncthreads();   // As reads done -> overlay Us
    #pragma unroll
    for (int r = 0; r < 2; ++r) {
        float* up = UA + (r0 + r) * 132 + j0;
        #pragma unroll
        for (int j = 0; j < 8; ++j) up[j] = accA[r][j] + bb1[j0 + j];
    }
    __syncthreads();
    // ---- LN(128)+ReLU on Us ----
    {
        int row = tid >> 3, q = tid & 7;
        const float* rp = UA + row * 132;
        float s = 0.f, sq = 0.f;
        #pragma unroll
        for (int i = 0; i < 16; ++i) { float v = rp[q + 8 * i]; s += v; sq += v * v; }
        ps[row * 8 + q] = s; psq[row * 8 + q] = sq;
    }
    __syncthreads();
    if (tid < 32) {
        float s = 0.f, sq = 0.f;
        #pragma unroll
        for (int j = 0; j < 8; ++j) { s += ps[tid * 8 + j]; sq += psq[tid * 8 + j]; }
        float mu = s * (1.f / 128.f);
        float var = sq * (1.f / 128.f) - mu * mu;
        mus[tid] = mu;
        rss[tid] = rsqrtf(fmaxf(var, 0.f) + LNE);
    }
    __syncthreads();
    {
        int row = tid >> 3, q = tid & 7;
        float mu = mus[row], rs = rss[row];
        float* rp = UA + row * 132;
        #pragma unroll
        for (int i = 0; i < 16; ++i) {
            int c = q + 8 * i;
            rp[c] = fmaxf((rp[c] - mu) * rs * lgv[c] + lbv[c], 0.f);
        }
    }
    __syncthreads();
    // ---- gemmB: Us(LDS) x W2(global) ----
    int o0 = tx * 4;
    float acc2[2][4] = {};
    #pragma unroll 4
    for (int k = 0; k < H2; ++k) {
        float4 b4 = *(const float4*)(W2l + (size_t)k * HH + o0);
        #pragma unroll
        for (int r = 0; r < 2; ++r) {
            float av = UA[(r0 + r) * 132 + k];
            acc2[r][0] += av * b4.x; acc2[r][1] += av * b4.y;
            acc2[r][2] += av * b4.z; acc2[r][3] += av * b4.w;
        }
    }
    float o[2][4];
    #pragma unroll
    for (int r = 0; r < 2; ++r) {
        int n = t * 32 + r0 + r;
        o[r][0] = acc2[r][0] + bb2[o0];     o[r][1] = acc2[r][1] + bb2[o0 + 1];
        o[r][2] = acc2[r][2] + bb2[o0 + 2]; o[r][3] = acc2[r][3] + bb2[o0 + 3];
        if (n < NN) {
            if (hres) {
                float4 hr = *(const float4*)(hres + (size_t)n * HH + o0);
                o[r][0] += hr.x; o[r][1] += hr.y; o[r][2] += hr.z; o[r][3] += hr.w;
            }
            float4 ov = {o[r][0], o[r][1], o[r][2], o[r][3]};
            *(float4*)(hout + (size_t)n * HH + o0) = ov;
        }
    }
    if (nlgl) {
        float g0 = nlgl[o0], g1 = nlgl[o0 + 1], g2 = nlgl[o0 + 2], g3 = nlgl[o0 + 3];
        float c0 = nlbl[o0], c1 = nlbl[o0 + 1], c2 = nlbl[o0 + 2], c3 = nlbl[o0 + 3];
        #pragma unroll
        for (int r = 0; r < 2; ++r) {
            int n = t * 32 + r0 + r;
            float s = o[r][0] + o[r][1] + o[r][2] + o[r][3];
            float sq = o[r][0]*o[r][0] + o[r][1]*o[r][1] + o[r][2]*o[r][2] + o[r][3]*o[r][3];
            #pragma unroll
            for (int m = 1; m < 16; m <<= 1) { s += __shfl_xor(s, m); sq += __shfl_xor(sq, m); }
            float mu = s * (1.f / 64.f);
            float var = sq * (1.f / 64.f) - mu * mu;
            float rs = rsqrtf(fmaxf(var, 0.f) + LNE);
            if (n < NN) {
                float y0v = fmaxf((o[r][0] - mu) * rs * g0 + c0, 0.f);
                float y1v = fmaxf((o[r][1] - mu) * rs * g1 + c1, 0.f);
                float y2v = fmaxf((o[r][2] - mu) * rs * g2 + c2, 0.f);
                float y3v = fmaxf((o[r][3] - mu) * rs * g3 + c3, 0.f);
                float4 yv = {y0v, y1v, y2v, y3v};
                *(float4*)(ynext + (size_t)n * HH + o0) = yv;
                ushort4 bv;
                bv.x = f2b(y0v); bv.y = f2b(y1v); bv.z = f2b(y2v); bv.w = f2b(y3v);
                *(ushort4*)(ybnext + (size_t)n * HH + o0) = bv;
            }
        }
    }
}

// ---------- fused final LN + both heads, GEMM-tile (64 nodes/block) ----------
__global__ __launch_bounds__(256) void k_outg(const float* __restrict__ h,
                                              const float* __restrict__ lng, const float* __restrict__ lnb,
                                              const float* __restrict__ gW, const float* __restrict__ gb,
                                              const float* __restrict__ nW, const float* __restrict__ nbp,
                                              float* __restrict__ dout, unsigned* __restrict__ genc) {
    __shared__ float As[64 * 68];
    __shared__ float Wc[64 * 40];
    __shared__ float Os[64 * 40];
    __shared__ float bs[40];
    __shared__ float lg[HH], lb[HH];
    __shared__ float ps[256], psq[256];
    __shared__ float mus[64], rss[64];
    int tid = threadIdx.x;
    int nb = blockIdx.x * 64;
    for (int i = tid; i < HH * ON; i += 256) { int k = i / ON, j = i - k * ON; Wc[k * 40 + j] = nW[i]; }
    for (int i = tid; i < HH * OC; i += 256) { int k = i / OC, j = i - k * OC; Wc[k * 40 + ON + j] = gW[i]; }
    if (tid < ON) bs[tid] = nbp[tid];
    else if (tid < 33) bs[tid] = gb[tid - ON];
    if (tid < HH) { lg[tid] = lng[tid]; lb[tid] = lnb[tid]; }
    {
        int row = tid >> 2, cb = (tid & 3) * 16;
        int n = nb + row;
        float4* dp = (float4*)(As + row * 68 + cb);
        if (n < NN) {
            const float4* sp = (const float4*)(h + (size_t)n * HH + cb);
            #pragma unroll
            for (int i = 0; i < 4; ++i) dp[i] = sp[i];
        } else {
            float4 z = {0.f, 0.f, 0.f, 0.f};
            #pragma unroll
            for (int i = 0; i < 4; ++i) dp[i] = z;
        }
    }
    __syncthreads();
    {
        int row = tid >> 2, q = tid & 3;
        const float* rp = As + row * 68;
        float s = 0.f, sq = 0.f;
        #pragma unroll
        for (int i = 0; i < 16; ++i) { float v = rp[q + 4 * i]; s += v; sq += v * v; }
        ps[tid] = s; psq[tid] = sq;
    }
    __syncthreads();
    if (tid < 64) {
        float s = ps[tid * 4] + ps[tid * 4 + 1] + ps[tid * 4 + 2] + ps[tid * 4 + 3];
        float sq = psq[tid * 4] + psq[tid * 4 + 1] + psq[tid * 4 + 2] + psq[tid * 4 + 3];
        float mu = s * (1.f / 64.f);
        float var = sq * (1.f / 64.f) - mu * mu;
        mus[tid] = mu;
        rss[tid] = rsqrtf(fmaxf(var, 0.f) + LNE);
    }
    __syncthreads();
    {
        int row = tid >> 2, q = tid & 3;
        float mu = mus[row], rs = rss[row];
        float* rp = As + row * 68;
        #pragma unroll
        for (int i = 0; i < 16; ++i) {
            int c = q + 4 * i;
            rp[c] = fmaxf((rp[c] - mu) * rs * lg[c] + lb[c], 0.f);
        }
    }
    __syncthreads();
    int tx = tid & 15, ty = tid >> 4;
    int r0 = ty * 4;
    float acc[4][3];
    #pragma unroll
    for (int r = 0; r < 4; ++r) {
        acc[r][0] = bs[tx]; acc[r][1] = bs[tx + 16]; acc[r][2] = bs[32];
    }
    #pragma unroll 4
    for (int k = 0; k < HH; ++k) {
        float w0 = Wc[k * 40 + tx];
        float w1 = Wc[k * 40 + 16 + tx];
        float w2 = Wc[k * 40 + 32];
        #pragma unroll
        for (int r = 0; r < 4; ++r) {
            float av = As[(r0 + r) * 68 + k];
            acc[r][0] += av * w0; acc[r][1] += av * w1; acc[r][2] += av * w2;
        }
    }
    #pragma unroll
    for (int r = 0; r < 4; ++r) {
        Os[(r0 + r) * 40 + tx] = acc[r][0];
        Os[(r0 + r) * 40 + 16 + tx] = acc[r][1];
        if (tx == 0) Os[(r0 + r) * 40 + 32] = acc[r][2];
    }
    __syncthreads();
    for (int i = tid; i < 64 * ON; i += 256) {
        int r = i / ON, j = i - r * ON;
        int n = nb + r;
        if (n < NN) dout[OC + (size_t)n * ON + j] = Os[r * 40 + j];
    }
    if (tid < OC) {
        int rmax = NN - nb; if (rmax > 64) rmax = 64;
        float m = -INFINITY;
        for (int r = 0; r < rmax; ++r) m = fmaxf(m, Os[r * 40 + ON + tid]);
        atomicMax(&genc[tid], fenc(m));
    }
}

__global__ void k_gdec(const unsigned* __restrict__ genc, float* __restrict__ dout) {
    int t = threadIdx.x;
    if (t < OC) dout[t] = fdec(genc[t]);
}

// ---------- launch ----------
extern "C" void kernel_launch(void* const* d_in, const int* in_sizes, int n_in,
                              void* d_out, int out_size, void* d_ws, size_t ws_size,
                              hipStream_t stream) {
    const float* x     = (const float*)d_in[0];
    const float* nodeW = (const float*)d_in[1];
    const float* nodeB = (const float*)d_in[2];
    const float* W1    = (const float*)d_in[3];
    const float* b1    = (const float*)d_in[4];
    const float* mlg   = (const float*)d_in[5];
    const float* mlb   = (const float*)d_in[6];
    const float* W2    = (const float*)d_in[7];
    const float* b2    = (const float*)d_in[8];
    const float* tt    = (const float*)d_in[9];
    const float* lng   = (const float*)d_in[10];
    const float* lnb   = (const float*)d_in[11];
    const int*   ei    = (const int*)d_in[12];
    const float* gW    = (const float*)d_in[13];
    const float* gb    = (const float*)d_in[14];
    const float* nW    = (const float*)d_in[15];
    const float* nbp   = (const float*)d_in[16];
    float* out = (float*)d_out;

    char* ws = (char*)d_ws;
    size_t off = 0;
    auto alloc = [&](size_t bytes) -> void* {
        void* p = ws + off;
        off = (off + bytes + 255) & ~(size_t)255;
        return p;
    };
    int* counts    = (int*)alloc((size_t)NN * 4);
    int* gcur      = (int*)alloc(64);
    unsigned* genc = (unsigned*)alloc(64);
    size_t zero_end = off;
    int2* rowse = (int2*)alloc((size_t)NN * 8);
    int* rank  = (int*)alloc((size_t)NE * 4);
    int* ssrc  = (int*)alloc((size_t)NE * 4);
    float* h   = (float*)alloc((size_t)NN * HH * 4);
    unsigned short* hbf = (unsigned short*)alloc((size_t)NN * HH * 2);
    float* y0  = (float*)alloc((size_t)NN * HH * 4);
    unsigned short* yb0 = (unsigned short*)alloc((size_t)NN * HH * 2);
    float* y1  = (float*)alloc((size_t)NN * HH * 4);
    unsigned short* yb1 = (unsigned short*)alloc((size_t)NN * HH * 2);

    const int* esrc = ei;
    const int* edst = ei + NE;

    hipMemsetAsync(d_ws, 0, zero_end, stream);

    k_hist2<<<(NE + 255) / 256, 256, 0, stream>>>(edst, counts, rank);
    k_scan<<<SCAN_BLOCKS, 256, 0, stream>>>(counts, rowse, gcur);
    k_scatter2<<<(NE + 255) / 256, 256, 0, stream>>>(esrc, edst, rank, rowse, ssrc);
    k_encoder<<<(NN + 3) / 4, 256, 0, stream>>>(x, nodeW, nodeB, h, hbf);

    for (int l = 0; l < NL; ++l) {
        const float* yin; const unsigned short* ybin;
        if (l == 0) { yin = h; ybin = hbf; }
        else if (((l - 1) & 1) == 0) { yin = y0; ybin = yb0; }
        else { yin = y1; ybin = yb1; }
        float* ynext = (l & 1) ? y1 : y0;
        unsigned short* ybnext = (l & 1) ? yb1 : yb0;
        bool last = (l == NL - 1);
        k_layer<<<T32, 256, 0, stream>>>(yin, ybin, rowse, ssrc, tt + l,
                                         W1 + (size_t)l * HH * H2, b1 + (size_t)l * H2,
                                         mlg + (size_t)l * H2, mlb + (size_t)l * H2,
                                         W2 + (size_t)l * H2 * HH, b2 + (size_t)l * HH,
                                         (l == 0) ? (const float*)nullptr : h, h,
                                         last ? (const float*)nullptr : lng + (size_t)(l + 1) * HH,
                                         last ? (const float*)nullptr : lnb + (size_t)(l + 1) * HH,
                                         ynext, ybnext);
    }
    k_outg<<<(NN + 63) / 64, 256, 0, stream>>>(h, lng, lnb, gW, gb, nW, nbp, out, genc);
    k_gdec<<<1, 64, 0, stream>>>(genc, out);
}